// Round 16
// baseline (122.574 us; speedup 1.0000x reference)
//
#include <hip/hip_runtime.h>
#include <hip/hip_bf16.h>

#define NB 8
#define CH 256
#define NN 4096
#define CQK 32
#define LOG2E 1.4426950408889634f

typedef __attribute__((ext_vector_type(4))) float f32x4;
typedef __attribute__((ext_vector_type(8))) short bf16x8;
typedef unsigned short u16;

static __device__ __forceinline__ u16 f2bf(float f) {
  unsigned int u = __float_as_uint(f);
  unsigned int r = (u + 0x7fffu + ((u >> 16) & 1u)) >> 16;
  return (u16)r;
}

// ---------------------------------------------------------------------------
// Kernel 1: weights -> bf16, FRAGMENT-PACKED (contiguous 1KB wave loads).
// ---------------------------------------------------------------------------
__global__ void prep_weights(const float* __restrict__ Wq, const float* __restrict__ bq,
                             const float* __restrict__ Wk, const float* __restrict__ bk,
                             const float* __restrict__ Wv,
                             u16* __restrict__ Wqkf, u16* __restrict__ Wvf,
                             float* __restrict__ bqk) {
  int i = blockIdx.x * 256 + threadIdx.x;   // 65536
  int o = i >> 8, c = i & 255;
  int kk = c >> 5, g2 = (c >> 3) & 3, j = c & 7;
  if (o < 64) {
    float wv = (o < 32) ? Wq[o * 256 + c] * LOG2E : Wk[(o - 32) * 256 + c];
    Wqkf[((((o >> 4) * 8 + kk) * 4 + g2) * 16 + (o & 15)) * 8 + j] = f2bf(wv);
  }
  Wvf[((((o >> 4) * 8 + kk) * 4 + g2) * 16 + (o & 15)) * 8 + j] = f2bf(Wv[i]);
  if (i < 64) bqk[i] = (i < 32) ? bq[i] * LOG2E : bk[i - 32];
}

// ---------------------------------------------------------------------------
// Kernel 2: FUSED transpose + both projections (r11, unchanged — verified).
// ---------------------------------------------------------------------------
__global__ __launch_bounds__(256, 2) void fused_proj(
    const float* __restrict__ x, const u16* __restrict__ Wqkf,
    const u16* __restrict__ Wvf, const float* __restrict__ bqk,
    const float* __restrict__ bv,
    u16* __restrict__ qbuf, u16* __restrict__ kbuf, u16* __restrict__ vbuf) {
  __shared__ __align__(128) char xt[64 * 512];
  const int b = blockIdx.y, n0 = blockIdx.x * 64;
  const int tid = threadIdx.x, w = tid >> 6, l = tid & 63, g = l >> 4, lr = l & 15;
  const f32x4 fzero = {0.f, 0.f, 0.f, 0.f};

  {
    const int nl = l, cl = w;
    const float* xp = x + (size_t)b * CH * NN + n0 + nl;
    char* xrow = xt + nl * 512;
    const int swz = (nl & 15) << 4;
#pragma unroll
    for (int p = 0; p < 32; ++p) {
      const int c = p * 8 + cl * 2;
      float f0 = xp[(size_t)c * NN], f1 = xp[(size_t)(c + 1) * NN];
      unsigned int pk = (unsigned int)f2bf(f0) | ((unsigned int)f2bf(f1) << 16);
      *(unsigned int*)(xrow + ((c * 2) ^ swz)) = pk;
    }
  }
  __syncthreads();

  const int aswz = lr << 4;

  {
    f32x4 acc[4];
#pragma unroll
    for (int ct = 0; ct < 4; ++ct) acc[ct] = fzero;
#pragma unroll
    for (int kk = 0; kk < 8; ++kk) {
      bf16x8 af = *(const bf16x8*)(xt + (w * 16 + lr) * 512 + ((kk * 64 + g * 16) ^ aswz));
#pragma unroll
      for (int ct = 0; ct < 4; ++ct) {
        bf16x8 bf = *(const bf16x8*)(Wqkf + (size_t)(((ct * 8 + kk) * 4 + g) * 16 + lr) * 8);
        acc[ct] = __builtin_amdgcn_mfma_f32_16x16x32_bf16(af, bf, acc[ct], 0, 0, 0);
      }
    }
#pragma unroll
    for (int ct = 0; ct < 4; ++ct) {
      const int col = ct * 16 + lr;
      const float bc = bqk[col];
#pragma unroll
      for (int r = 0; r < 4; ++r) {
        const int row = n0 + w * 16 + g * 4 + r;
        u16 h = f2bf(acc[ct][r] + bc);
        if (col < 32) qbuf[((size_t)(b * NN + row)) * 32 + col] = h;
        else          kbuf[((size_t)(b * NN + row)) * 32 + (col - 32)] = h;
      }
    }
  }

  {
    f32x4 vacc[4][4];
#pragma unroll
    for (int ct = 0; ct < 4; ++ct)
#pragma unroll
      for (int mt = 0; mt < 4; ++mt) vacc[ct][mt] = fzero;
#pragma unroll
    for (int kk = 0; kk < 8; ++kk) {
      bf16x8 bfm[4];
#pragma unroll
      for (int mt = 0; mt < 4; ++mt)
        bfm[mt] = *(const bf16x8*)(xt + (mt * 16 + lr) * 512 + ((kk * 64 + g * 16) ^ aswz));
#pragma unroll
      for (int ct = 0; ct < 4; ++ct) {
        bf16x8 af = *(const bf16x8*)(Wvf + (size_t)((((w * 4 + ct) * 8 + kk) * 4 + g) * 16 + lr) * 8);
#pragma unroll
        for (int mt = 0; mt < 4; ++mt)
          vacc[ct][mt] = __builtin_amdgcn_mfma_f32_16x16x32_bf16(af, bfm[mt], vacc[ct][mt], 0, 0, 0);
      }
    }
#pragma unroll
    for (int ct = 0; ct < 4; ++ct) {
#pragma unroll
      for (int mt = 0; mt < 4; ++mt) {
        const int m = n0 + mt * 16 + lr;
#pragma unroll
        for (int r = 0; r < 4; ++r) {
          const int ch = w * 64 + ct * 16 + g * 4 + r;
          vbuf[((size_t)(b * 128 + (m >> 5)) * 256 + ch) * 32 + (m & 31)] = f2bf(vacc[ct][mt][r] + bv[ch]);
        }
      }
    }
  }
}

// ---------------------------------------------------------------------------
// Kernel 3: fused attention, 128q blocks, 8 waves, BK=128, 32 barriers.
// SINGLE merged post-barrier region per step: PWRITE(P(T+1)) then
// hand-interleaved {PVQ quarter (16 MFMA + 8 ds_read)} x {QK2 (2 MFMA +
// 8 exp + pack)} so MFMA / VALU / LDS pipes are co-busy instead of phase-
// serialized (r15 decomposition: the three pipes sum to the whole step).
// Pipeline: region T consumes P(T) & V(T), writes P(T+1) (computed T-1),
// computes QK(T+2), loads K(T+3) and V(T+1). One barrier per step.
// P layout: two 128B-row half-tiles per buffer (r15's low-conflict form).
// ---------------------------------------------------------------------------
#define KLOAD2(T, sub) (*(const bf16x8*)(kp + (size_t)((((T) & 31) * 128) + (sub) * 16) * 32))
#define VLOAD(mg, ct) (*(const bf16x8*)(vp + (size_t)((mg) & 127) * 8192 + (ct) * 512))

#define EXPP(S, PW, MASK) {                                                                   \
  float e0 = __builtin_amdgcn_exp2f(S[0]);                                                    \
  float e1 = __builtin_amdgcn_exp2f(S[1]);                                                    \
  float e2 = __builtin_amdgcn_exp2f(S[2]);                                                    \
  float e3 = __builtin_amdgcn_exp2f(S[3]);                                                    \
  lsum += (MASK) * ((e0 + e1) + (e2 + e3));                                                   \
  PW.x = __builtin_amdgcn_perm(__float_as_uint(e1) + 0x8000u, __float_as_uint(e0) + 0x8000u, 0x07060302u); \
  PW.y = __builtin_amdgcn_perm(__float_as_uint(e3) + 0x8000u, __float_as_uint(e2) + 0x8000u, 0x07060302u); \
}

// 2 QK MFMAs + softmax for two 16-m subtiles
#define QK2(KX, KY, PWX, PWY, MASK) {                                                         \
  f32x4 sx = __builtin_amdgcn_mfma_f32_16x16x32_bf16(KX, qf, fzero, 0, 0, 0);                 \
  f32x4 sy = __builtin_amdgcn_mfma_f32_16x16x32_bf16(KY, qf, fzero, 0, 0, 0);                 \
  EXPP(sx, PWX, MASK); EXPP(sy, PWY, MASK);                                                   \
}

#define PBAR() do {                                  \
  __builtin_amdgcn_sched_barrier(0);                 \
  asm volatile("s_waitcnt lgkmcnt(0)");              \
  __builtin_amdgcn_s_barrier();                      \
  __builtin_amdgcn_sched_barrier(0);                 \
} while (0)

// write P step-tile: halves L (pw0..3) and H (pw4..7), r10-exact addressing
#define PWRITE(BUF) {                                                                         \
  char* pl = (char*)Pb + (BUF) * 32768 + prow * 128;                                          \
  *(uint2*)(pl + ((0 * 32 + g * 8) ^ wswz)) = pw0;                                            \
  *(uint2*)(pl + ((1 * 32 + g * 8) ^ wswz)) = pw1;                                            \
  *(uint2*)(pl + ((2 * 32 + g * 8) ^ wswz)) = pw2;                                            \
  *(uint2*)(pl + ((3 * 32 + g * 8) ^ wswz)) = pw3;                                            \
  char* ph = pl + 16384;                                                                      \
  *(uint2*)(ph + ((0 * 32 + g * 8) ^ wswz)) = pw4;                                            \
  *(uint2*)(ph + ((1 * 32 + g * 8) ^ wswz)) = pw5;                                            \
  *(uint2*)(ph + ((2 * 32 + g * 8) ^ wswz)) = pw6;                                            \
  *(uint2*)(ph + ((3 * 32 + g * 8) ^ wswz)) = pw7;                                            \
}

// one 32-m quarter: QTR>>1 selects half-tile, QTR&1 selects 64B sub-offset
#define PVQ(BUF, QTR, VA, VB) {                                                               \
  const char* prb = (const char*)Pb + (BUF) * 32768 + ((QTR) >> 1) * 16384;                   \
  _Pragma("unroll")                                                                           \
  for (int nt = 0; nt < 8; ++nt) {                                                            \
    const int row = nt * 16 + lr;                                                             \
    const int rs = (row & 7) << 4;                                                            \
    bf16x8 pa = *(const bf16x8*)(prb + row * 128 + ((((QTR) & 1) * 64 + g * 16) ^ rs));       \
    oacc[nt][0] = __builtin_amdgcn_mfma_f32_16x16x32_bf16(VA, pa, oacc[nt][0], 0, 0, 0);      \
    oacc[nt][1] = __builtin_amdgcn_mfma_f32_16x16x32_bf16(VB, pa, oacc[nt][1], 0, 0, 0);      \
  }                                                                                           \
}

__global__ __launch_bounds__(512, 2) void attn_fused(
    const u16* __restrict__ qb, const u16* __restrict__ kbuf,
    const u16* __restrict__ vbuf, const float* __restrict__ x,
    const float* __restrict__ gamma_p, float* __restrict__ out) {
  __shared__ __align__(128) char Pb[2][2][16384];   // [buf][half][128 x 128B]
  __shared__ float lsum_s[128];

  const int b = blockIdx.x;          // batch -> XCD pinning
  const int n0 = blockIdx.y * 128;
  const int tid = threadIdx.x, w = tid >> 6, l = tid & 63, g = l >> 4, lr = l & 15;
  const float gamma0 = gamma_p[0];
  const f32x4 fzero = {0.f, 0.f, 0.f, 0.f};

  bf16x8 qf = *(const bf16x8*)(qb + ((size_t)b * NN + n0 + w * 16 + lr) * 32 + g * 8);

  const u16* kp = kbuf + (size_t)b * (NN * 32) + (size_t)lr * 32 + g * 8;
  const u16* vp = vbuf + (size_t)b * 1048576 + (size_t)(w * 32 + lr) * 32 + g * 8;

  f32x4 oacc[8][2];
#pragma unroll
  for (int nt = 0; nt < 8; ++nt)
#pragma unroll
    for (int ct = 0; ct < 2; ++ct) oacc[nt][ct] = fzero;
  float lsum = 0.f;

  const int prow = w * 16 + lr;
  const int wswz = (prow & 7) << 4;

  bf16x8 kA0, kA1, kA2, kA3, kA4, kA5, kA6, kA7;
  bf16x8 kB0, kB1, kB2, kB3, kB4, kB5, kB6, kB7;
  bf16x8 v0, v1, v2, v3, v4, v5, v6, v7;
  uint2 pw0, pw1, pw2, pw3, pw4, pw5, pw6, pw7;

  // ---- prologue ----
  // P(0) -> Pb[0]
  kA0 = KLOAD2(0, 0); kA1 = KLOAD2(0, 1); kA2 = KLOAD2(0, 2); kA3 = KLOAD2(0, 3);
  kA4 = KLOAD2(0, 4); kA5 = KLOAD2(0, 5); kA6 = KLOAD2(0, 6); kA7 = KLOAD2(0, 7);
  QK2(kA0, kA1, pw0, pw1, 1.0f); QK2(kA2, kA3, pw2, pw3, 1.0f);
  QK2(kA4, kA5, pw4, pw5, 1.0f); QK2(kA6, kA7, pw6, pw7, 1.0f);
  PWRITE(0);
  // pw = P(1) (written at region 0)
  kA0 = KLOAD2(1, 0); kA1 = KLOAD2(1, 1); kA2 = KLOAD2(1, 2); kA3 = KLOAD2(1, 3);
  kA4 = KLOAD2(1, 4); kA5 = KLOAD2(1, 5); kA6 = KLOAD2(1, 6); kA7 = KLOAD2(1, 7);
  QK2(kA0, kA1, pw0, pw1, 1.0f); QK2(kA2, kA3, pw2, pw3, 1.0f);
  QK2(kA4, kA5, pw4, pw5, 1.0f); QK2(kA6, kA7, pw6, pw7, 1.0f);
  // kA = K(2) for region 0's QK(2); V(0) h0
  kA0 = KLOAD2(2, 0); kA1 = KLOAD2(2, 1); kA2 = KLOAD2(2, 2); kA3 = KLOAD2(2, 3);
  kA4 = KLOAD2(2, 4); kA5 = KLOAD2(2, 5); kA6 = KLOAD2(2, 6); kA7 = KLOAD2(2, 7);
  v0 = VLOAD(0, 0); v1 = VLOAD(0, 1); v2 = VLOAD(1, 0); v3 = VLOAD(1, 1);

  for (int T2 = 0; T2 < 16; ++T2) {
    const float mk = (T2 < 15) ? 1.0f : 0.0f;  // masks QK(32)/QK(33)
    // ===== region T = 2*T2 (even): read Pb[0], write P(T+1)->Pb[1] =====
    {
      const int T = 2 * T2;
      PBAR();
      PWRITE(1);
      v4 = VLOAD(4 * T + 2, 0); v5 = VLOAD(4 * T + 2, 1);
      v6 = VLOAD(4 * T + 3, 0); v7 = VLOAD(4 * T + 3, 1);
      PVQ(0, 0, v0, v1);
      QK2(kA0, kA1, pw0, pw1, mk);
      PVQ(0, 1, v2, v3);
      QK2(kA2, kA3, pw2, pw3, mk);
      PVQ(0, 2, v4, v5);
      QK2(kA4, kA5, pw4, pw5, mk);
      PVQ(0, 3, v6, v7);
      QK2(kA6, kA7, pw6, pw7, mk);
      // loads for the future: K(T+3) -> kB, V(T+1) h0 -> v0..3
      kB0 = KLOAD2(T + 3, 0); kB1 = KLOAD2(T + 3, 1); kB2 = KLOAD2(T + 3, 2); kB3 = KLOAD2(T + 3, 3);
      kB4 = KLOAD2(T + 3, 4); kB5 = KLOAD2(T + 3, 5); kB6 = KLOAD2(T + 3, 6); kB7 = KLOAD2(T + 3, 7);
      v0 = VLOAD(4 * T + 4, 0); v1 = VLOAD(4 * T + 4, 1);
      v2 = VLOAD(4 * T + 5, 0); v3 = VLOAD(4 * T + 5, 1);
    }
    // ===== region T = 2*T2+1 (odd): read Pb[1], write P(T+1)->Pb[0] =====
    {
      const int T = 2 * T2 + 1;
      PBAR();
      PWRITE(0);
      v4 = VLOAD(4 * T + 2, 0); v5 = VLOAD(4 * T + 2, 1);
      v6 = VLOAD(4 * T + 3, 0); v7 = VLOAD(4 * T + 3, 1);
      PVQ(1, 0, v0, v1);
      QK2(kB0, kB1, pw0, pw1, mk);
      PVQ(1, 1, v2, v3);
      QK2(kB2, kB3, pw2, pw3, mk);
      PVQ(1, 2, v4, v5);
      QK2(kB4, kB5, pw4, pw5, mk);
      PVQ(1, 3, v6, v7);
      QK2(kB6, kB7, pw6, pw7, mk);
      kA0 = KLOAD2(T + 3, 0); kA1 = KLOAD2(T + 3, 1); kA2 = KLOAD2(T + 3, 2); kA3 = KLOAD2(T + 3, 3);
      kA4 = KLOAD2(T + 3, 4); kA5 = KLOAD2(T + 3, 5); kA6 = KLOAD2(T + 3, 6); kA7 = KLOAD2(T + 3, 7);
      v0 = VLOAD(4 * T + 4, 0); v1 = VLOAD(4 * T + 4, 1);
      v2 = VLOAD(4 * T + 5, 0); v3 = VLOAD(4 * T + 5, 1);
    }
  }

  // ---- epilogue: share lsum, normalize, gamma*O + x ----
  lsum += __shfl_xor(lsum, 16);
  lsum += __shfl_xor(lsum, 32);
  if (l < 16) lsum_s[w * 16 + lr] = lsum;
  __syncthreads();

  const size_t bbase = (size_t)b * CH * NN;
#pragma unroll
  for (int nt = 0; nt < 8; ++nt) {
    const int q = nt * 16 + lr;
    const float linv = 1.f / lsum_s[q];
    const int n = n0 + q;
#pragma unroll
    for (int ct = 0; ct < 2; ++ct) {
      const int cbase = w * 32 + ct * 16 + g * 4;
#pragma unroll
      for (int r = 0; r < 4; ++r) {
        const size_t off = bbase + (size_t)(cbase + r) * NN + n;
        out[off] = gamma0 * (oacc[nt][ct][r] * linv) + x[off];
      }
    }
  }
}

// ---------------------------------------------------------------------------
extern "C" void kernel_launch(void* const* d_in, const int* in_sizes, int n_in,
                              void* d_out, int out_size, void* d_ws, size_t ws_size,
                              hipStream_t stream) {
  const float* x     = (const float*)d_in[0];
  const float* Wq    = (const float*)d_in[1];
  const float* bq    = (const float*)d_in[2];
  const float* Wk    = (const float*)d_in[3];
  const float* bk    = (const float*)d_in[4];
  const float* Wv    = (const float*)d_in[5];
  const float* bv    = (const float*)d_in[6];
  const float* gamma = (const float*)d_in[7];
  float* out = (float*)d_out;

  char* ws = (char*)d_ws;
  u16*   qbuf = (u16*)(ws);                 // [B,N,32] packed      2,097,152 B
  u16*   kbuf = (u16*)(ws + 2097152);       // [B,N,32] packed      2,097,152 B
  u16*   vbuf = (u16*)(ws + 4194304);       // v fragments         16,777,216 B
  u16*   Wqkf = (u16*)(ws + 20971520);      // packed frags            32,768 B
  u16*   Wvf  = (u16*)(ws + 21004288);      // packed frags           131,072 B
  float* bqk  = (float*)(ws + 21135360);    // [64] f32                   256 B

  prep_weights<<<256, 256, 0, stream>>>(Wq, bq, Wk, bk, Wv, Wqkf, Wvf, bqk);
  fused_proj<<<dim3(64, 8), 256, 0, stream>>>(x, Wqkf, Wvf, bqk, bv, qbuf, kbuf, vbuf);
  attn_fused<<<dim3(8, 32), 512, 0, stream>>>(qbuf, kbuf, vbuf, x, gamma, out);
}

// Round 17
// 109.490 us; speedup vs baseline: 1.1195x; 1.1195x over previous
//
#include <hip/hip_runtime.h>
#include <hip/hip_bf16.h>

#define NB 8
#define CH 256
#define NN 4096
#define CQK 32
#define LOG2E 1.4426950408889634f

typedef __attribute__((ext_vector_type(4))) float f32x4;
typedef __attribute__((ext_vector_type(8))) short bf16x8;
typedef unsigned short u16;

static __device__ __forceinline__ u16 f2bf(float f) {
  unsigned int u = __float_as_uint(f);
  unsigned int r = (u + 0x7fffu + ((u >> 16) & 1u)) >> 16;
  return (u16)r;
}

// ---------------------------------------------------------------------------
// Kernel 1: weights -> bf16, FRAGMENT-PACKED (contiguous 1KB wave loads).
// ---------------------------------------------------------------------------
__global__ void prep_weights(const float* __restrict__ Wq, const float* __restrict__ bq,
                             const float* __restrict__ Wk, const float* __restrict__ bk,
                             const float* __restrict__ Wv,
                             u16* __restrict__ Wqkf, u16* __restrict__ Wvf,
                             float* __restrict__ bqk) {
  int i = blockIdx.x * 256 + threadIdx.x;   // 65536
  int o = i >> 8, c = i & 255;
  int kk = c >> 5, g2 = (c >> 3) & 3, j = c & 7;
  if (o < 64) {
    float wv = (o < 32) ? Wq[o * 256 + c] * LOG2E : Wk[(o - 32) * 256 + c];
    Wqkf[((((o >> 4) * 8 + kk) * 4 + g2) * 16 + (o & 15)) * 8 + j] = f2bf(wv);
  }
  Wvf[((((o >> 4) * 8 + kk) * 4 + g2) * 16 + (o & 15)) * 8 + j] = f2bf(Wv[i]);
  if (i < 64) bqk[i] = (i < 32) ? bq[i] * LOG2E : bk[i - 32];
}

// ---------------------------------------------------------------------------
// Kernel 2: FUSED transpose + both projections (r11, unchanged — verified).
// ---------------------------------------------------------------------------
__global__ __launch_bounds__(256, 2) void fused_proj(
    const float* __restrict__ x, const u16* __restrict__ Wqkf,
    const u16* __restrict__ Wvf, const float* __restrict__ bqk,
    const float* __restrict__ bv,
    u16* __restrict__ qbuf, u16* __restrict__ kbuf, u16* __restrict__ vbuf) {
  __shared__ __align__(128) char xt[64 * 512];
  const int b = blockIdx.y, n0 = blockIdx.x * 64;
  const int tid = threadIdx.x, w = tid >> 6, l = tid & 63, g = l >> 4, lr = l & 15;
  const f32x4 fzero = {0.f, 0.f, 0.f, 0.f};

  {
    const int nl = l, cl = w;
    const float* xp = x + (size_t)b * CH * NN + n0 + nl;
    char* xrow = xt + nl * 512;
    const int swz = (nl & 15) << 4;
#pragma unroll
    for (int p = 0; p < 32; ++p) {
      const int c = p * 8 + cl * 2;
      float f0 = xp[(size_t)c * NN], f1 = xp[(size_t)(c + 1) * NN];
      unsigned int pk = (unsigned int)f2bf(f0) | ((unsigned int)f2bf(f1) << 16);
      *(unsigned int*)(xrow + ((c * 2) ^ swz)) = pk;
    }
  }
  __syncthreads();

  const int aswz = lr << 4;

  {
    f32x4 acc[4];
#pragma unroll
    for (int ct = 0; ct < 4; ++ct) acc[ct] = fzero;
#pragma unroll
    for (int kk = 0; kk < 8; ++kk) {
      bf16x8 af = *(const bf16x8*)(xt + (w * 16 + lr) * 512 + ((kk * 64 + g * 16) ^ aswz));
#pragma unroll
      for (int ct = 0; ct < 4; ++ct) {
        bf16x8 bf = *(const bf16x8*)(Wqkf + (size_t)(((ct * 8 + kk) * 4 + g) * 16 + lr) * 8);
        acc[ct] = __builtin_amdgcn_mfma_f32_16x16x32_bf16(af, bf, acc[ct], 0, 0, 0);
      }
    }
#pragma unroll
    for (int ct = 0; ct < 4; ++ct) {
      const int col = ct * 16 + lr;
      const float bc = bqk[col];
#pragma unroll
      for (int r = 0; r < 4; ++r) {
        const int row = n0 + w * 16 + g * 4 + r;
        u16 h = f2bf(acc[ct][r] + bc);
        if (col < 32) qbuf[((size_t)(b * NN + row)) * 32 + col] = h;
        else          kbuf[((size_t)(b * NN + row)) * 32 + (col - 32)] = h;
      }
    }
  }

  {
    f32x4 vacc[4][4];
#pragma unroll
    for (int ct = 0; ct < 4; ++ct)
#pragma unroll
      for (int mt = 0; mt < 4; ++mt) vacc[ct][mt] = fzero;
#pragma unroll
    for (int kk = 0; kk < 8; ++kk) {
      bf16x8 bfm[4];
#pragma unroll
      for (int mt = 0; mt < 4; ++mt)
        bfm[mt] = *(const bf16x8*)(xt + (mt * 16 + lr) * 512 + ((kk * 64 + g * 16) ^ aswz));
#pragma unroll
      for (int ct = 0; ct < 4; ++ct) {
        bf16x8 af = *(const bf16x8*)(Wvf + (size_t)((((w * 4 + ct) * 8 + kk) * 4 + g) * 16 + lr) * 8);
#pragma unroll
        for (int mt = 0; mt < 4; ++mt)
          vacc[ct][mt] = __builtin_amdgcn_mfma_f32_16x16x32_bf16(af, bfm[mt], vacc[ct][mt], 0, 0, 0);
      }
    }
#pragma unroll
    for (int ct = 0; ct < 4; ++ct) {
#pragma unroll
      for (int mt = 0; mt < 4; ++mt) {
        const int m = n0 + mt * 16 + lr;
#pragma unroll
        for (int r = 0; r < 4; ++r) {
          const int ch = w * 64 + ct * 16 + g * 4 + r;
          vbuf[((size_t)(b * 128 + (m >> 5)) * 256 + ch) * 32 + (m & 31)] = f2bf(vacc[ct][mt][r] + bv[ch]);
        }
      }
    }
  }
}

// ---------------------------------------------------------------------------
// Kernel 3: fused attention — r10's kernel VERBATIM (best measured: 94.0us,
// MfmaUtil 35.9, conflicts 2.1M). 128-query blocks, 8 waves / 512 threads.
//   Wave w: QK^T+softmax for its OWN 16-q tile (4 MFMA + 16 exp, complete
//   in-wave lsum), PV for 32 channels x 128 queries (32 MFMA).
// Software-pipelined P across the lgkm-only barrier; BK=64 double buffer;
// setprio on PV. Grid dim3(8,32): batch -> XCD pinning; 256 blocks = 1/CU.
// (r11-r16 structural variants — 32x32 PV, q/ch splits, BK=128, merged
// interleave — all measured equal or worse; reverted.)
// ---------------------------------------------------------------------------
#define KLOAD(t, sub) (*(const bf16x8*)(kp + (size_t)((((t) & 63) * 64) + (sub) * 16) * 32))
#define VLOAD(mg, ct) (*(const bf16x8*)(vp + (size_t)((mg) & 127) * 8192 + (ct) * 512))

#define EXPP(S, PW, MASK) {                                                                   \
  float e0 = __builtin_amdgcn_exp2f(S[0]);                                                    \
  float e1 = __builtin_amdgcn_exp2f(S[1]);                                                    \
  float e2 = __builtin_amdgcn_exp2f(S[2]);                                                    \
  float e3 = __builtin_amdgcn_exp2f(S[3]);                                                    \
  lsum += (MASK) * ((e0 + e1) + (e2 + e3));                                                   \
  PW.x = __builtin_amdgcn_perm(__float_as_uint(e1) + 0x8000u, __float_as_uint(e0) + 0x8000u, 0x07060302u); \
  PW.y = __builtin_amdgcn_perm(__float_as_uint(e3) + 0x8000u, __float_as_uint(e2) + 0x8000u, 0x07060302u); \
}

#define PBAR() do {                                  \
  __builtin_amdgcn_sched_barrier(0);                 \
  asm volatile("s_waitcnt lgkmcnt(0)");              \
  __builtin_amdgcn_s_barrier();                      \
  __builtin_amdgcn_sched_barrier(0);                 \
} while (0)

// post-barrier: read P(t) (128 rows) from Pb[BUF], write P(t+1) -> Pb[BUF^1],
// 32 PV MFMA. V0/V1 = m-half 0, V2/V3 = m-half 1.
#define PVPHASE(BUF, V0, V1, V2, V3) {                                                        \
  const char* prb = (const char*)Pb + (BUF) * 16384;                                          \
  char* pdst = (char*)Pb + ((BUF) ^ 1) * 16384 + prow * 128;                                  \
  *(uint2*)(pdst + ((0 * 32 + g * 8) ^ wswz)) = pw0;                                          \
  *(uint2*)(pdst + ((1 * 32 + g * 8) ^ wswz)) = pw1;                                          \
  *(uint2*)(pdst + ((2 * 32 + g * 8) ^ wswz)) = pw2;                                          \
  *(uint2*)(pdst + ((3 * 32 + g * 8) ^ wswz)) = pw3;                                          \
  __builtin_amdgcn_s_setprio(1);                                                              \
  _Pragma("unroll")                                                                           \
  for (int nt = 0; nt < 8; ++nt) {                                                            \
    const int row = nt * 16 + lr;                                                             \
    const int rs = (row & 7) << 4;                                                            \
    bf16x8 pa0 = *(const bf16x8*)(prb + row * 128 + ((g * 16) ^ rs));                         \
    bf16x8 pa1 = *(const bf16x8*)(prb + row * 128 + ((64 + g * 16) ^ rs));                    \
    oacc[nt][0] = __builtin_amdgcn_mfma_f32_16x16x32_bf16(V0, pa0, oacc[nt][0], 0, 0, 0);     \
    oacc[nt][1] = __builtin_amdgcn_mfma_f32_16x16x32_bf16(V1, pa0, oacc[nt][1], 0, 0, 0);     \
    oacc[nt][0] = __builtin_amdgcn_mfma_f32_16x16x32_bf16(V2, pa1, oacc[nt][0], 0, 0, 0);     \
    oacc[nt][1] = __builtin_amdgcn_mfma_f32_16x16x32_bf16(V3, pa1, oacc[nt][1], 0, 0, 0);     \
  }                                                                                           \
  __builtin_amdgcn_s_setprio(0);                                                              \
}

__global__ __launch_bounds__(512, 2) void attn_fused(
    const u16* __restrict__ qb, const u16* __restrict__ kbuf,
    const u16* __restrict__ vbuf, const float* __restrict__ x,
    const float* __restrict__ gamma_p, float* __restrict__ out) {
  __shared__ __align__(128) char Pb[2][128 * 128];
  __shared__ float lpart[8][16];

  const int b = blockIdx.x;          // batch -> XCD pinning
  const int n0 = blockIdx.y * 128;
  const int tid = threadIdx.x, w = tid >> 6, l = tid & 63, g = l >> 4, lr = l & 15;
  const float gamma0 = gamma_p[0];
  const f32x4 fzero = {0.f, 0.f, 0.f, 0.f};

  // q fragment (B-operand) for this wave's own 16-query tile
  bf16x8 qf = *(const bf16x8*)(qb + ((size_t)b * NN + n0 + w * 16 + lr) * 32 + g * 8);

  const u16* kp = kbuf + (size_t)b * (NN * 32) + (size_t)lr * 32 + g * 8;
  const u16* vp = vbuf + (size_t)b * 1048576 + (size_t)(w * 32 + lr) * 32 + g * 8;

  f32x4 oacc[8][2];
#pragma unroll
  for (int nt = 0; nt < 8; ++nt)
#pragma unroll
    for (int ct = 0; ct < 2; ++ct) oacc[nt][ct] = fzero;
  float lsum = 0.f;

  const int prow = w * 16 + lr;
  const int wswz = (prow & 7) << 4;

  // ---- prologue: prepare tile 0 into Pb[0]; prefetch V(0), K(1) ----
  bf16x8 kA0 = KLOAD(0, 0), kA1 = KLOAD(0, 1), kA2 = KLOAD(0, 2), kA3 = KLOAD(0, 3);
  bf16x8 vA0 = VLOAD(0, 0), vA1 = VLOAD(0, 1), vA2 = VLOAD(1, 0), vA3 = VLOAD(1, 1);
  bf16x8 kB0 = KLOAD(1, 0), kB1 = KLOAD(1, 1), kB2 = KLOAD(1, 2), kB3 = KLOAD(1, 3);
  bf16x8 vB0, vB1, vB2, vB3;
  uint2 pw0, pw1, pw2, pw3;
  {
    f32x4 s0 = __builtin_amdgcn_mfma_f32_16x16x32_bf16(kA0, qf, fzero, 0, 0, 0);
    f32x4 s1 = __builtin_amdgcn_mfma_f32_16x16x32_bf16(kA1, qf, fzero, 0, 0, 0);
    f32x4 s2 = __builtin_amdgcn_mfma_f32_16x16x32_bf16(kA2, qf, fzero, 0, 0, 0);
    f32x4 s3 = __builtin_amdgcn_mfma_f32_16x16x32_bf16(kA3, qf, fzero, 0, 0, 0);
    EXPP(s0, pw0, 1.0f); EXPP(s1, pw1, 1.0f); EXPP(s2, pw2, 1.0f); EXPP(s3, pw3, 1.0f);
    char* pdst = (char*)Pb + prow * 128;
    *(uint2*)(pdst + ((0 * 32 + g * 8) ^ wswz)) = pw0;
    *(uint2*)(pdst + ((1 * 32 + g * 8) ^ wswz)) = pw1;
    *(uint2*)(pdst + ((2 * 32 + g * 8) ^ wswz)) = pw2;
    *(uint2*)(pdst + ((3 * 32 + g * 8) ^ wswz)) = pw3;
  }

  for (int it2 = 0; it2 < 32; ++it2) {
    // ============ phase even: consume tile 2*it2; prepare 2*it2+1 ============
    {
      const int tn = 2 * it2 + 1;
      f32x4 s0 = __builtin_amdgcn_mfma_f32_16x16x32_bf16(kB0, qf, fzero, 0, 0, 0);
      f32x4 s1 = __builtin_amdgcn_mfma_f32_16x16x32_bf16(kB1, qf, fzero, 0, 0, 0);
      f32x4 s2 = __builtin_amdgcn_mfma_f32_16x16x32_bf16(kB2, qf, fzero, 0, 0, 0);
      f32x4 s3 = __builtin_amdgcn_mfma_f32_16x16x32_bf16(kB3, qf, fzero, 0, 0, 0);
      kA0 = KLOAD(tn + 1, 0); kA1 = KLOAD(tn + 1, 1); kA2 = KLOAD(tn + 1, 2); kA3 = KLOAD(tn + 1, 3);
      vB0 = VLOAD(2 * tn, 0); vB1 = VLOAD(2 * tn, 1);
      vB2 = VLOAD(2 * tn + 1, 0); vB3 = VLOAD(2 * tn + 1, 1);
      EXPP(s0, pw0, 1.0f); EXPP(s1, pw1, 1.0f); EXPP(s2, pw2, 1.0f); EXPP(s3, pw3, 1.0f);
      PBAR();
      PVPHASE(0, vA0, vA1, vA2, vA3);
    }
    // ============ phase odd: consume 2*it2+1; prepare 2*it2+2 ============
    {
      const int tn = 2 * it2 + 2;
      const float tmask = (it2 < 31) ? 1.0f : 0.0f;  // exclude wrapped tile 64
      f32x4 s0 = __builtin_amdgcn_mfma_f32_16x16x32_bf16(kA0, qf, fzero, 0, 0, 0);
      f32x4 s1 = __builtin_amdgcn_mfma_f32_16x16x32_bf16(kA1, qf, fzero, 0, 0, 0);
      f32x4 s2 = __builtin_amdgcn_mfma_f32_16x16x32_bf16(kA2, qf, fzero, 0, 0, 0);
      f32x4 s3 = __builtin_amdgcn_mfma_f32_16x16x32_bf16(kA3, qf, fzero, 0, 0, 0);
      kB0 = KLOAD(tn + 1, 0); kB1 = KLOAD(tn + 1, 1); kB2 = KLOAD(tn + 1, 2); kB3 = KLOAD(tn + 1, 3);
      vA0 = VLOAD(2 * tn, 0); vA1 = VLOAD(2 * tn, 1);
      vA2 = VLOAD(2 * tn + 1, 0); vA3 = VLOAD(2 * tn + 1, 1);
      EXPP(s0, pw0, tmask); EXPP(s1, pw1, tmask); EXPP(s2, pw2, tmask); EXPP(s3, pw3, tmask);
      PBAR();
      PVPHASE(1, vB0, vB1, vB2, vB3);
    }
  }

  // ---- epilogue: lsum complete per wave; share across waves, write out ----
  lsum += __shfl_xor(lsum, 16);
  lsum += __shfl_xor(lsum, 32);
  if (l < 16) lpart[w][lr] = lsum;
  __syncthreads();

  const size_t bbase = (size_t)b * CH * NN;
#pragma unroll
  for (int nt = 0; nt < 8; ++nt) {
    const float linv = 1.f / lpart[nt][lr];
    const int ncol = n0 + nt * 16 + lr;
#pragma unroll
    for (int ct = 0; ct < 2; ++ct) {
      const int cbase = w * 32 + ct * 16 + g * 4;
#pragma unroll
      for (int r = 0; r < 4; ++r) {
        const size_t off = bbase + (size_t)(cbase + r) * NN + ncol;
        out[off] = gamma0 * (oacc[nt][ct][r] * linv) + x[off];
      }
    }
  }
}

// ---------------------------------------------------------------------------
extern "C" void kernel_launch(void* const* d_in, const int* in_sizes, int n_in,
                              void* d_out, int out_size, void* d_ws, size_t ws_size,
                              hipStream_t stream) {
  const float* x     = (const float*)d_in[0];
  const float* Wq    = (const float*)d_in[1];
  const float* bq    = (const float*)d_in[2];
  const float* Wk    = (const float*)d_in[3];
  const float* bk    = (const float*)d_in[4];
  const float* Wv    = (const float*)d_in[5];
  const float* bv    = (const float*)d_in[6];
  const float* gamma = (const float*)d_in[7];
  float* out = (float*)d_out;

  char* ws = (char*)d_ws;
  u16*   qbuf = (u16*)(ws);                 // [B,N,32] packed      2,097,152 B
  u16*   kbuf = (u16*)(ws + 2097152);       // [B,N,32] packed      2,097,152 B
  u16*   vbuf = (u16*)(ws + 4194304);       // v fragments         16,777,216 B
  u16*   Wqkf = (u16*)(ws + 20971520);      // packed frags            32,768 B
  u16*   Wvf  = (u16*)(ws + 21004288);      // packed frags           131,072 B
  float* bqk  = (float*)(ws + 21135360);    // [64] f32                   256 B

  prep_weights<<<256, 256, 0, stream>>>(Wq, bq, Wk, bk, Wv, Wqkf, Wvf, bqk);
  fused_proj<<<dim3(64, 8), 256, 0, stream>>>(x, Wqkf, Wvf, bqk, bv, qbuf, kbuf, vbuf);
  attn_fused<<<dim3(8, 32), 512, 0, stream>>>(qbuf, kbuf, vbuf, x, gamma, out);
}